// Round 5
// baseline (3176.422 us; speedup 1.0000x reference)
//
#include <hip/hip_runtime.h>
#include <hip/hip_bf16.h>

typedef __bf16 bf16_t;
typedef __bf16 bf16x8 __attribute__((ext_vector_type(8)));
typedef __bf16 bf16x4 __attribute__((ext_vector_type(4)));
typedef float f32x4 __attribute__((ext_vector_type(4)));

#define Bn 8
#define Tn 2048
#define Cn 2048
#define Hn 32
#define HSn 64
#define CT 64

static const long SZ = (long)Bn * Tn * Cn;   // 33,554,432 elements

__device__ __forceinline__ void g2l16(const void* g, void* l) {
  __builtin_amdgcn_global_load_lds((const __attribute__((address_space(1))) void*)g,
                                   (__attribute__((address_space(3))) void*)l,
                                   16, 0, 0);
}

// ---------------------------------------------------------------------------
// Weight transpose + fp32 -> split bf16 hi/lo: Oh/Ol[n][k] = split(W[k][n])
// ---------------------------------------------------------------------------
__global__ __launch_bounds__(256)
void transps(const float* w0, const float* w1, const float* w2,
             const float* w3, const float* w4, bf16_t* oh, bf16_t* ol)
{
  const float* Ws[5] = {w0, w1, w2, w3, w4};
  const float* W = Ws[blockIdx.z];
  const long base = (long)blockIdx.z * ((long)Cn * Cn);
  __shared__ float tile[64][65];
  const int xx = threadIdx.x & 63;
  const int y4 = threadIdx.x >> 6;
  const int bx = blockIdx.x * 64, by = blockIdx.y * 64;
#pragma unroll
  for (int i = 0; i < 16; ++i) {
    int row = i * 4 + y4;
    tile[row][xx] = W[(long)(by + row) * Cn + bx + xx];
  }
  __syncthreads();
#pragma unroll
  for (int i = 0; i < 16; ++i) {
    int row = i * 4 + y4;
    float v = tile[xx][row];
    bf16_t hi = (bf16_t)v;
    long o = base + (long)(bx + row) * Cn + by + xx;
    oh[o] = hi;
    ol[o] = (bf16_t)(v - (float)hi);
  }
}

// ---------------------------------------------------------------------------
// Split x split GEMM, 256x256 tile, BK=32, 8 waves (2M x 4N), counted-vmcnt
// phase pipeline (T3+T4), setprio around MFMA clusters (T5), T2 slot-XOR
// swizzle (source-side pre-swizzle, read-slot XOR; conflicts measured 0).
//
// Per K-tile t (buffers cb=t&1 / nb=cb^1), two phases:
//   P1: wait -> barrier -> issue stage group 1 (t+1) -> read ah,bh -> 32 MFMA
//       ah*bh -> [amode0: mix+split A(t+1) in regs, ds_write to nb]
//   P2: wait -> barrier -> issue stage group 2 (t+1) -> read al,bl -> 64 MFMA
//       al*bh + ah*bl
// Staging grouped by consumption order so waits never drain to 0:
//   amode1: g1={Ah,Bh} g2={Al,Bl}, P1 vmcnt(4), P2 vmcnt(4)
//   amode0: g1={Bh,Bl (all B)}, A via ds_write in P1; P1 vmcnt(2)+lgkmcnt(0)
//           (drains prior A-writes for cross-wave visibility), P2 vmcnt(4)
// Last tile stages tile 0 into the dead buffer to keep counts uniform.
// Race bound: issues/writes sit AFTER the phase barrier; the overwritten
// region (tile t-1's arrays) was last read one full phase earlier, and all
// waves passed that phase's barrier -> safe with 2 barriers/K-tile.
//
// emode 0: bf16 store. 1: silu(acc)*(Zh+Zl) split store. 2: fp32. 3: split.
// ---------------------------------------------------------------------------
template <int AMODE, int EMODE>
__global__ __launch_bounds__(512)
void gemmx(const float* __restrict__ X, const float* __restrict__ tm,
           const bf16_t* __restrict__ Ah, const bf16_t* __restrict__ Al,
           const bf16_t* __restrict__ BTh, const bf16_t* __restrict__ BTl,
           void* __restrict__ Cp,
           const bf16_t* __restrict__ Zh, const bf16_t* __restrict__ Zl,
           bf16_t* __restrict__ Gh, bf16_t* __restrict__ Gl)
{
  __shared__ __align__(16) bf16_t lAh[2][256 * 32];
  __shared__ __align__(16) bf16_t lAl[2][256 * 32];
  __shared__ __align__(16) bf16_t lBh[2][256 * 32];
  __shared__ __align__(16) bf16_t lBl[2][256 * 32];

  const int tid = threadIdx.x;
  const int wv = tid >> 6;
  const int lane = tid & 63;
  const int wmw = (wv >> 2) & 1;       // M half: rows wmw*128
  const int wnw = wv & 3;              // N quarter: cols wnw*64
  const long m0 = (long)blockIdx.y * 256;
  const int n0 = blockIdx.x * 256;

  // staging: per array 256x32 elems = 2 rounds of 512 thr x 8 elems (16 B)
  const int e0 = tid * 8;
  const int e1 = 4096 + tid * 8;
  const int r0 = tid >> 2;             // 0..127 (round 1: +128)
  const int s0 = tid & 3;
  const int c0 = (s0 ^ ((r0 >> 1) & 3)) << 3;   // swizzled source column
  // (r0+128)>>1 & 3 == (r0>>1)&3 -> round-1 column identical
  const long aoff0 = (m0 + r0) * Cn + c0;
  const long aoff1 = (m0 + r0 + 128) * Cn + c0;
  const long boff0 = (long)(n0 + r0) * Cn + c0;
  const long boff1 = (long)(n0 + r0 + 128) * Cn + c0;
  const bool p0ok = ((int)(m0 & (Tn - 1)) | r0) != 0;  // row r0 has prev step

  const int kg = lane >> 4;
  const int lr = lane & 15;
  const int kS = (kg ^ ((lr >> 1) & 3)) * 8;   // read-side swizzled slot

  // amode0: register mix + hi/lo split of A tile -> ds_write (linear dest)
  auto mixA = [&](long kc2, int dst) {
    float xf[16], pf[16], tf[8];
    const long a0 = aoff0 + kc2, a1 = aoff1 + kc2;
    *(f32x4*)&xf[0]  = *(const f32x4*)&X[a0];
    *(f32x4*)&xf[4]  = *(const f32x4*)&X[a0 + 4];
    *(f32x4*)&xf[8]  = *(const f32x4*)&X[a1];
    *(f32x4*)&xf[12] = *(const f32x4*)&X[a1 + 4];
    if (p0ok) {
      *(f32x4*)&pf[0] = *(const f32x4*)&X[a0 - Cn];
      *(f32x4*)&pf[4] = *(const f32x4*)&X[a0 - Cn + 4];
    } else {
#pragma unroll
      for (int q = 0; q < 8; ++q) pf[q] = 0.f;
    }
    *(f32x4*)&pf[8]  = *(const f32x4*)&X[a1 - Cn];
    *(f32x4*)&pf[12] = *(const f32x4*)&X[a1 - Cn + 4];
    *(f32x4*)&tf[0] = *(const f32x4*)&tm[kc2 + c0];
    *(f32x4*)&tf[4] = *(const f32x4*)&tm[kc2 + c0 + 4];
    bf16x8 h0, l0, h1, l1;
#pragma unroll
    for (int q = 0; q < 8; ++q) {
      float o0 = pf[q] + tf[q] * (xf[q] - pf[q]);
      bf16_t hi0 = (bf16_t)o0;
      h0[q] = hi0; l0[q] = (bf16_t)(o0 - (float)hi0);
      float o1 = pf[8 + q] + tf[q] * (xf[8 + q] - pf[8 + q]);
      bf16_t hi1 = (bf16_t)o1;
      h1[q] = hi1; l1[q] = (bf16_t)(o1 - (float)hi1);
    }
    *(bf16x8*)&lAh[dst][e0] = h0; *(bf16x8*)&lAl[dst][e0] = l0;
    *(bf16x8*)&lAh[dst][e1] = h1; *(bf16x8*)&lAl[dst][e1] = l1;
  };

  // ---- prologue: stage tile 0 (oldest-first order matches in-loop waits)
  if constexpr (AMODE == 0) {
    mixA(0, 0);
    g2l16(BTh + boff0, &lBh[0][e0]);
    g2l16(BTh + boff1, &lBh[0][e1]);
    __builtin_amdgcn_sched_barrier(0);
    g2l16(BTl + boff0, &lBl[0][e0]);
    g2l16(BTl + boff1, &lBl[0][e1]);
  } else {
    g2l16(Ah + aoff0, &lAh[0][e0]);
    g2l16(Ah + aoff1, &lAh[0][e1]);
    g2l16(BTh + boff0, &lBh[0][e0]);
    g2l16(BTh + boff1, &lBh[0][e1]);
    __builtin_amdgcn_sched_barrier(0);
    g2l16(Al + aoff0, &lAl[0][e0]);
    g2l16(Al + aoff1, &lAl[0][e1]);
    g2l16(BTl + boff0, &lBl[0][e0]);
    g2l16(BTl + boff1, &lBl[0][e1]);
  }

  const int NT = Cn / 32;   // 64
  f32x4 acc[8][4] = {};
  bf16x8 ah[8], bh[4];

  for (int t = 0; t < NT; ++t) {
    const int cb = t & 1, nb = cb ^ 1;
    const int tn = (t + 1 < NT) ? t + 1 : 0;   // wrap: dead-buffer stage
    const long kc = (long)tn * 32;

    // ---------------- phase 1 : ah*bh ----------------
    if constexpr (AMODE == 0) {
      asm volatile("s_waitcnt vmcnt(2) lgkmcnt(0)" ::: "memory");
    } else {
      asm volatile("s_waitcnt vmcnt(4)" ::: "memory");
    }
    __builtin_amdgcn_sched_barrier(0);
    __builtin_amdgcn_s_barrier();
    __builtin_amdgcn_sched_barrier(0);
    if constexpr (AMODE == 0) {
      g2l16(BTh + boff0 + kc, &lBh[nb][e0]);
      g2l16(BTh + boff1 + kc, &lBh[nb][e1]);
      g2l16(BTl + boff0 + kc, &lBl[nb][e0]);
      g2l16(BTl + boff1 + kc, &lBl[nb][e1]);
    } else {
      g2l16(Ah + aoff0 + kc, &lAh[nb][e0]);
      g2l16(Ah + aoff1 + kc, &lAh[nb][e1]);
      g2l16(BTh + boff0 + kc, &lBh[nb][e0]);
      g2l16(BTh + boff1 + kc, &lBh[nb][e1]);
    }
#pragma unroll
    for (int i = 0; i < 8; ++i)
      ah[i] = *(const bf16x8*)&lAh[cb][(wmw * 128 + i * 16 + lr) * 32 + kS];
#pragma unroll
    for (int j = 0; j < 4; ++j)
      bh[j] = *(const bf16x8*)&lBh[cb][(wnw * 64 + j * 16 + lr) * 32 + kS];
    __builtin_amdgcn_s_setprio(1);
#pragma unroll
    for (int i = 0; i < 8; ++i)
#pragma unroll
      for (int j = 0; j < 4; ++j)
        acc[i][j] = __builtin_amdgcn_mfma_f32_16x16x32_bf16(ah[i], bh[j], acc[i][j], 0, 0, 0);
    __builtin_amdgcn_s_setprio(0);
    if constexpr (AMODE == 0) mixA(kc, nb);

    // ---------------- phase 2 : al*bh + ah*bl ----------------
    asm volatile("s_waitcnt vmcnt(4)" ::: "memory");
    __builtin_amdgcn_sched_barrier(0);
    __builtin_amdgcn_s_barrier();
    __builtin_amdgcn_sched_barrier(0);
    if constexpr (AMODE == 1) {
      g2l16(Al + aoff0 + kc, &lAl[nb][e0]);
      g2l16(Al + aoff1 + kc, &lAl[nb][e1]);
      g2l16(BTl + boff0 + kc, &lBl[nb][e0]);
      g2l16(BTl + boff1 + kc, &lBl[nb][e1]);
    }
    bf16x8 al[8], bl[4];
#pragma unroll
    for (int i = 0; i < 8; ++i)
      al[i] = *(const bf16x8*)&lAl[cb][(wmw * 128 + i * 16 + lr) * 32 + kS];
#pragma unroll
    for (int j = 0; j < 4; ++j)
      bl[j] = *(const bf16x8*)&lBl[cb][(wnw * 64 + j * 16 + lr) * 32 + kS];
    __builtin_amdgcn_s_setprio(1);
#pragma unroll
    for (int i = 0; i < 8; ++i) {
#pragma unroll
      for (int j = 0; j < 4; ++j)
        acc[i][j] = __builtin_amdgcn_mfma_f32_16x16x32_bf16(al[i], bh[j], acc[i][j], 0, 0, 0);
#pragma unroll
      for (int j = 0; j < 4; ++j)
        acc[i][j] = __builtin_amdgcn_mfma_f32_16x16x32_bf16(ah[i], bl[j], acc[i][j], 0, 0, 0);
    }
    __builtin_amdgcn_s_setprio(0);
  }

  // C/D layout: col = lane&15, row = (lane>>4)*4 + reg   [m89-verified]
  const int qr = lane >> 4;
  const int cnn = lane & 15;
#pragma unroll
  for (int i = 0; i < 8; ++i) {
#pragma unroll
    for (int j = 0; j < 4; ++j) {
#pragma unroll
      for (int rg = 0; rg < 4; ++rg) {
        long row = m0 + wmw * 128 + i * 16 + qr * 4 + rg;
        int col = n0 + wnw * 64 + j * 16 + cnn;
        long off = row * Cn + col;
        float vv = acc[i][j][rg];
        if constexpr (EMODE == 0) {
          ((bf16_t*)Cp)[off] = (bf16_t)vv;
        } else if constexpr (EMODE == 1) {
          float z = (float)Zh[off] + (float)Zl[off];
          float zg = vv / (1.f + __expf(-vv)) * z;
          bf16_t hi = (bf16_t)zg;
          Gh[off] = hi;
          Gl[off] = (bf16_t)(zg - (float)hi);
        } else if constexpr (EMODE == 2) {
          ((float*)Cp)[off] = vv;
        } else {   // 3: split store
          bf16_t hi = (bf16_t)vv;
          Gh[off] = hi;
          Gl[off] = (bf16_t)(vv - (float)hi);
        }
      }
    }
  }
}

// ---------------------------------------------------------------------------
// wkv5 recurrence + fused /8 + GroupNorm(64, one-pass) + ln scale/shift.
// One block per (b,h), 1024 threads (4 waves/SIMD; 512 was latency-bound at
// 2 waves/SIMD, VALUBusy 43.7%). Thread (j=tid>>4, ic=tid&15) owns
// S[i0..i0+3][j] fp32 (i0 = ic*4). j-invariant ap_t = r_t . (u * k_t)
// hoisted into the staging commit (thread layout (tl=tid>>4, cc=(tid&15)*4)
// matches (t, i-slice)) and broadcast via sA. Inner loop: 1 ds_read_b128
// each for rr/kk + 12 VALU + 4-level shuffle reduce. r (hi+lo), k, v staged
// per 64-step chunk in LDS fp32, double-buffered, register prefetch 2
// chunks ahead. GroupNorm via one interleaved butterfly. z written SPLIT
// hi/lo in-place over consumed rh-slot/k-slot.
// ---------------------------------------------------------------------------
__global__ __launch_bounds__(1024)
void wkv5(const bf16_t* Rh, const bf16_t* __restrict__ Rl,
          const bf16_t* Km, const bf16_t* __restrict__ Vm,
          const float* __restrict__ decay, const float* __restrict__ faaaa,
          const float* __restrict__ lw, const float* __restrict__ lb,
          bf16_t* Zh, bf16_t* Zl)
{
  const int bh = blockIdx.x;
  const int b = bh >> 5;          // H = 32
  const int h = bh & 31;
  const int tid = threadIdx.x;
  const int j = tid >> 4;         // value column 0..63
  const int ic = tid & 15;        // i-slice 0..15
  const int i0 = ic * 4;

  float w[4], u[4], S[4];
#pragma unroll
  for (int q = 0; q < 4; ++q) {
    w[q] = expf(-expf(decay[h * 64 + i0 + q]));
    u[q] = faaaa[h * 64 + i0 + q];
    S[q] = 0.f;
  }

  __shared__ __align__(16) float sR[2][CT * 64];   // 32 KB
  __shared__ __align__(16) float sK[2][CT * 64];   // 32 KB
  __shared__ __align__(16) float sV[2][CT * 64];   // 32 KB
  __shared__ __align__(16) float sY[CT * 64];      // 16 KB
  __shared__ float sA[2][CT];                      // 0.5 KB  (ap per t)

  const int e = tid * 4;          // 1024*4 = 4096 = CT*64
  const int tl = e >> 6;          // = tid>>4 : timestep within chunk
  const int cc = e & 63;          // = (tid&15)*4 : channel slice (== i0)
  const long gbase = (long)b * Tn * Cn + h * 64 + cc;

  const int wv = tid >> 6;        // wave 0..15
  const int ln = tid & 63;
  const float lwv = lw[h * 64 + ln];
  const float lbv = lb[h * 64 + ln];

  bf16x4 prh, prl, pk, pv;
  auto issue = [&](int cch) {
    const long g = gbase + (long)(cch * CT + tl) * Cn;
    prh = *(const bf16x4*)&Rh[g];
    prl = *(const bf16x4*)&Rl[g];
    pk  = *(const bf16x4*)&Km[g];
    pv  = *(const bf16x4*)&Vm[g];
  };
  auto commit = [&](int bufA) {
    float apv = 0.f;
#pragma unroll
    for (int q = 0; q < 4; ++q) {
      float rf = (float)prh[q] + (float)prl[q];
      float kf = (float)pk[q];
      sR[bufA][e + q] = rf;
      sK[bufA][e + q] = kf;
      sV[bufA][e + q] = (float)pv[q];
      apv += (rf * u[q]) * kf;    // thread's u-slice matches cc == i0
    }
    apv += __shfl_xor(apv, 1);
    apv += __shfl_xor(apv, 2);
    apv += __shfl_xor(apv, 4);
    apv += __shfl_xor(apv, 8);
    if (ic == 0) sA[bufA][tl] = apv;
  };

  issue(0); commit(0);
  __syncthreads();
  issue(1);

  const int NC = Tn / CT;   // 32
  for (int cch = 0; cch < NC; ++cch) {
    const int buf = cch & 1;
#pragma unroll 4
    for (int t = 0; t < CT; ++t) {
      float rr[4], kk[4];
      *(f32x4*)&rr[0] = *(const f32x4*)&sR[buf][t * 64 + i0];
      *(f32x4*)&kk[0] = *(const f32x4*)&sK[buf][t * 64 + i0];
      float vj = sV[buf][t * 64 + j];
      float yp = 0.f;
#pragma unroll
      for (int q = 0; q < 4; ++q) {
        yp += rr[q] * S[q];
        S[q] = w[q] * S[q] + kk[q] * vj;
      }
      yp += __shfl_xor(yp, 1);
      yp += __shfl_xor(yp, 2);
      yp += __shfl_xor(yp, 4);
      yp += __shfl_xor(yp, 8);
      if (ic == 0) sY[t * 64 + j] = (yp + sA[buf][t] * vj) * 0.125f;
    }
    if (cch + 1 < NC) commit((cch + 1) & 1);
    __syncthreads();
    if (cch + 2 < NC) issue(cch + 2);

    const long zrow0 = ((long)b * Tn + (long)cch * CT) * Cn + h * 64 + ln;
#pragma unroll
    for (int q = 0; q < 4; ++q) {
      const int t = wv * 4 + q;
      float val = sY[t * 64 + ln];
      float s = val, s2 = val * val;
#pragma unroll
      for (int off = 1; off < 64; off <<= 1) {
        s  += __shfl_xor(s, off);
        s2 += __shfl_xor(s2, off);
      }
      float mu = s * (1.f / 64.f);
      float var = fmaxf(s2 * (1.f / 64.f) - mu * mu, 0.f);
      float rs = rsqrtf(var + 1e-5f);
      float zv = (val - mu) * rs * lwv + lbv;
      bf16_t zh = (bf16_t)zv;
      Zh[zrow0 + (long)t * Cn] = zh;
      Zl[zrow0 + (long)t * Cn] = (bf16_t)(zv - (float)zh);
    }
    __syncthreads();
  }
}

// ---------------------------------------------------------------------------
extern "C" void kernel_launch(void* const* d_in, const int* in_sizes, int n_in,
                              void* d_out, int out_size, void* d_ws, size_t ws_size,
                              hipStream_t stream)
{
  const float* x    = (const float*)d_in[0];
  const float* tmk  = (const float*)d_in[1];
  const float* tmv  = (const float*)d_in[2];
  const float* tmr  = (const float*)d_in[3];
  const float* tmg  = (const float*)d_in[4];
  const float* tdec = (const float*)d_in[5];
  const float* tfaa = (const float*)d_in[6];
  const float* Wr   = (const float*)d_in[7];
  const float* Wk   = (const float*)d_in[8];
  const float* Wv   = (const float*)d_in[9];
  const float* Wg   = (const float*)d_in[10];
  const float* Wo   = (const float*)d_in[11];
  const float* lnw  = (const float*)d_in[12];
  const float* lnb  = (const float*)d_in[13];

  // ws layout (218.1 MB):
  //   [0, 41.9MB)      wTh : 5 transposed weight hi
  //   [41.9, 83.9MB)   wTl : 5 transposed weight lo
  //   sl0: v,    then zg_hi
  //   sl1: r_lo, then zg_lo
  // d_out (134 MB fp32 = 2 bf16 slots):
  //   d0a: r_hi, then z_hi;  d0b: k, then z_lo;  finally fp32 out.
  char* ws = (char*)d_ws;
  const long WSZ = (long)Cn * Cn;
  const long SZB = SZ * 2;                  // 67,108,864 B per bf16 slot
  bf16_t* wTh = (bf16_t*)ws;
  bf16_t* wTl = (bf16_t*)(ws + 5 * WSZ * 2);
  bf16_t* sl0 = (bf16_t*)(ws + 10 * WSZ * 2);
  bf16_t* sl1 = (bf16_t*)(ws + 10 * WSZ * 2 + SZB);
  bf16_t* d0a = (bf16_t*)d_out;
  bf16_t* d0b = (bf16_t*)d_out + SZ;

  const dim3 gGrid(8, 64, 1);   // 256x256 tiles over [16384, 2048]

  transps<<<dim3(32, 32, 5), 256, 0, stream>>>(Wr, Wk, Wv, Wg, Wo, wTh, wTl);

  // r = mix(x,tmr) @ Wr, split -> hi d0a, lo sl1
  gemmx<0, 3><<<gGrid, 512, 0, stream>>>(x, tmr, nullptr, nullptr,
                                         wTh + 0 * WSZ, wTl + 0 * WSZ, nullptr,
                                         nullptr, nullptr, d0a, sl1);
  // k = mix(x,tmk) @ Wk -> bf16 d0b
  gemmx<0, 0><<<gGrid, 512, 0, stream>>>(x, tmk, nullptr, nullptr,
                                         wTh + 1 * WSZ, wTl + 1 * WSZ, d0b,
                                         nullptr, nullptr, nullptr, nullptr);
  // v = mix(x,tmv) @ Wv -> bf16 sl0
  gemmx<0, 0><<<gGrid, 512, 0, stream>>>(x, tmv, nullptr, nullptr,
                                         wTh + 2 * WSZ, wTl + 2 * WSZ, sl0,
                                         nullptr, nullptr, nullptr, nullptr);

  // wkv5 + /8 + groupnorm -> z split: hi over d0a (r_hi), lo over d0b (k)
  wkv5<<<256, 1024, 0, stream>>>(d0a, sl1, d0b, sl0, tdec, tfaa, lnw, lnb,
                                 d0a, d0b);

  // zg = silu(mix(x,tmg) @ Wg) * (z_hi+z_lo), split -> hi sl0, lo sl1
  gemmx<0, 1><<<gGrid, 512, 0, stream>>>(x, tmg, nullptr, nullptr,
                                         wTh + 3 * WSZ, wTl + 3 * WSZ, nullptr,
                                         d0a, d0b, sl0, sl1);

  // out = (zg_hi+zg_lo) @ Wo -> fp32 d_out
  gemmx<1, 2><<<gGrid, 512, 0, stream>>>(nullptr, nullptr, sl0, sl1,
                                         wTh + 4 * WSZ, wTl + 4 * WSZ, d_out,
                                         nullptr, nullptr, nullptr, nullptr);
}

// Round 6
// 2956.008 us; speedup vs baseline: 1.0746x; 1.0746x over previous
//
#include <hip/hip_runtime.h>
#include <hip/hip_bf16.h>

typedef __bf16 bf16_t;
typedef __bf16 bf16x8 __attribute__((ext_vector_type(8)));
typedef float f32x4 __attribute__((ext_vector_type(4)));

#define Bn 8
#define Tn 2048
#define Cn 2048
#define Hn 32
#define HSn 64
#define CT 64

static const long SZ = (long)Bn * Tn * Cn;   // 33,554,432 elements

__device__ __forceinline__ void g2l16(const void* g, void* l) {
  __builtin_amdgcn_global_load_lds((const __attribute__((address_space(1))) void*)g,
                                   (__attribute__((address_space(3))) void*)l,
                                   16, 0, 0);
}

// DPP sum step on the VALU pipe (avoids ds_swizzle on the shared LDS pipe).
// CTRL: 0xB1 quad_perm [1,0,3,2] (xor1) ; 0x4E quad_perm [2,3,0,1] (xor2) ;
// 0x141 row_half_mirror (pairs across quads within 8) ; 0x140 row_mirror
// (pairs across 8s within 16). Valid sum-tree levels when applied in order.
template <int CTRL>
__device__ __forceinline__ float dppadd(float x) {
  int yi = __builtin_amdgcn_update_dpp(__float_as_int(x), __float_as_int(x),
                                       CTRL, 0xf, 0xf, false);
  return x + __int_as_float(yi);
}

// ---------------------------------------------------------------------------
// Weight transpose + fp32 -> split bf16 hi/lo: Oh/Ol[n][k] = split(W[k][n])
// ---------------------------------------------------------------------------
__global__ __launch_bounds__(256)
void transps(const float* w0, const float* w1, const float* w2,
             const float* w3, const float* w4, bf16_t* oh, bf16_t* ol)
{
  const float* Ws[5] = {w0, w1, w2, w3, w4};
  const float* W = Ws[blockIdx.z];
  const long base = (long)blockIdx.z * ((long)Cn * Cn);
  __shared__ float tile[64][65];
  const int xx = threadIdx.x & 63;
  const int y4 = threadIdx.x >> 6;
  const int bx = blockIdx.x * 64, by = blockIdx.y * 64;
#pragma unroll
  for (int i = 0; i < 16; ++i) {
    int row = i * 4 + y4;
    tile[row][xx] = W[(long)(by + row) * Cn + bx + xx];
  }
  __syncthreads();
#pragma unroll
  for (int i = 0; i < 16; ++i) {
    int row = i * 4 + y4;
    float v = tile[xx][row];
    bf16_t hi = (bf16_t)v;
    long o = base + (long)(bx + row) * Cn + by + xx;
    oh[o] = hi;
    ol[o] = (bf16_t)(v - (float)hi);
  }
}

// ---------------------------------------------------------------------------
// Split x split GEMM, 256x256 tile, BK=32, 8 waves (2M x 4N), counted-vmcnt
// phase pipeline (T3+T4), setprio around MFMA clusters (T5), T2 slot-XOR
// swizzle (source-side pre-swizzle, read-slot XOR; conflicts measured 0).
//
// Per K-tile t (buffers cb=t&1 / nb=cb^1), two phases:
//   P1: wait -> barrier -> issue stage group 1 (t+1) -> read ah,bh -> 32 MFMA
//       ah*bh -> [amode0: mix+split A(t+1) in regs, ds_write to nb]
//   P2: wait -> barrier -> issue stage group 2 (t+1) -> read al,bl -> 64 MFMA
//       al*bh + ah*bl
// Staging grouped by consumption order so waits never drain to 0:
//   amode1: g1={Ah,Bh} g2={Al,Bl}, P1 vmcnt(4), P2 vmcnt(4)
//   amode0: g1={Bh,Bl (all B)}, A via ds_write in P1; P1 vmcnt(2)+lgkmcnt(0)
//           (drains prior A-writes for cross-wave visibility), P2 vmcnt(4)
// Last tile stages tile 0 into the dead buffer to keep counts uniform.
// Race bound: issues/writes sit AFTER the phase barrier; the overwritten
// region (tile t-1's arrays) was last read one full phase earlier, and all
// waves passed that phase's barrier -> safe with 2 barriers/K-tile.
//
// emode 0: bf16 store. 1: silu(acc)*(Zh+Zl) split store. 2: fp32. 3: split.
// ---------------------------------------------------------------------------
template <int AMODE, int EMODE>
__global__ __launch_bounds__(512)
void gemmx(const float* __restrict__ X, const float* __restrict__ tm,
           const bf16_t* __restrict__ Ah, const bf16_t* __restrict__ Al,
           const bf16_t* __restrict__ BTh, const bf16_t* __restrict__ BTl,
           void* __restrict__ Cp,
           const bf16_t* __restrict__ Zh, const bf16_t* __restrict__ Zl,
           bf16_t* __restrict__ Gh, bf16_t* __restrict__ Gl)
{
  __shared__ __align__(16) bf16_t lAh[2][256 * 32];
  __shared__ __align__(16) bf16_t lAl[2][256 * 32];
  __shared__ __align__(16) bf16_t lBh[2][256 * 32];
  __shared__ __align__(16) bf16_t lBl[2][256 * 32];

  const int tid = threadIdx.x;
  const int wv = tid >> 6;
  const int lane = tid & 63;
  const int wmw = (wv >> 2) & 1;       // M half: rows wmw*128
  const int wnw = wv & 3;              // N quarter: cols wnw*64
  const long m0 = (long)blockIdx.y * 256;
  const int n0 = blockIdx.x * 256;

  // staging: per array 256x32 elems = 2 rounds of 512 thr x 8 elems (16 B)
  const int e0 = tid * 8;
  const int e1 = 4096 + tid * 8;
  const int r0 = tid >> 2;             // 0..127 (round 1: +128)
  const int s0 = tid & 3;
  const int c0 = (s0 ^ ((r0 >> 1) & 3)) << 3;   // swizzled source column
  // (r0+128)>>1 & 3 == (r0>>1)&3 -> round-1 column identical
  const long aoff0 = (m0 + r0) * Cn + c0;
  const long aoff1 = (m0 + r0 + 128) * Cn + c0;
  const long boff0 = (long)(n0 + r0) * Cn + c0;
  const long boff1 = (long)(n0 + r0 + 128) * Cn + c0;
  const bool p0ok = ((int)(m0 & (Tn - 1)) | r0) != 0;  // row r0 has prev step

  const int kg = lane >> 4;
  const int lr = lane & 15;
  const int kS = (kg ^ ((lr >> 1) & 3)) * 8;   // read-side swizzled slot

  // amode0: register mix + hi/lo split of A tile -> ds_write (linear dest)
  auto mixA = [&](long kc2, int dst) {
    float xf[16], pf[16], tf[8];
    const long a0 = aoff0 + kc2, a1 = aoff1 + kc2;
    *(f32x4*)&xf[0]  = *(const f32x4*)&X[a0];
    *(f32x4*)&xf[4]  = *(const f32x4*)&X[a0 + 4];
    *(f32x4*)&xf[8]  = *(const f32x4*)&X[a1];
    *(f32x4*)&xf[12] = *(const f32x4*)&X[a1 + 4];
    if (p0ok) {
      *(f32x4*)&pf[0] = *(const f32x4*)&X[a0 - Cn];
      *(f32x4*)&pf[4] = *(const f32x4*)&X[a0 - Cn + 4];
    } else {
#pragma unroll
      for (int q = 0; q < 8; ++q) pf[q] = 0.f;
    }
    *(f32x4*)&pf[8]  = *(const f32x4*)&X[a1 - Cn];
    *(f32x4*)&pf[12] = *(const f32x4*)&X[a1 - Cn + 4];
    *(f32x4*)&tf[0] = *(const f32x4*)&tm[kc2 + c0];
    *(f32x4*)&tf[4] = *(const f32x4*)&tm[kc2 + c0 + 4];
    bf16x8 h0, l0, h1, l1;
#pragma unroll
    for (int q = 0; q < 8; ++q) {
      float o0 = pf[q] + tf[q] * (xf[q] - pf[q]);
      bf16_t hi0 = (bf16_t)o0;
      h0[q] = hi0; l0[q] = (bf16_t)(o0 - (float)hi0);
      float o1 = pf[8 + q] + tf[q] * (xf[8 + q] - pf[8 + q]);
      bf16_t hi1 = (bf16_t)o1;
      h1[q] = hi1; l1[q] = (bf16_t)(o1 - (float)hi1);
    }
    *(bf16x8*)&lAh[dst][e0] = h0; *(bf16x8*)&lAl[dst][e0] = l0;
    *(bf16x8*)&lAh[dst][e1] = h1; *(bf16x8*)&lAl[dst][e1] = l1;
  };

  // ---- prologue: stage tile 0 (oldest-first order matches in-loop waits)
  if constexpr (AMODE == 0) {
    mixA(0, 0);
    g2l16(BTh + boff0, &lBh[0][e0]);
    g2l16(BTh + boff1, &lBh[0][e1]);
    __builtin_amdgcn_sched_barrier(0);
    g2l16(BTl + boff0, &lBl[0][e0]);
    g2l16(BTl + boff1, &lBl[0][e1]);
  } else {
    g2l16(Ah + aoff0, &lAh[0][e0]);
    g2l16(Ah + aoff1, &lAh[0][e1]);
    g2l16(BTh + boff0, &lBh[0][e0]);
    g2l16(BTh + boff1, &lBh[0][e1]);
    __builtin_amdgcn_sched_barrier(0);
    g2l16(Al + aoff0, &lAl[0][e0]);
    g2l16(Al + aoff1, &lAl[0][e1]);
    g2l16(BTl + boff0, &lBl[0][e0]);
    g2l16(BTl + boff1, &lBl[0][e1]);
  }

  const int NT = Cn / 32;   // 64
  f32x4 acc[8][4] = {};
  bf16x8 ah[8], bh[4];

  for (int t = 0; t < NT; ++t) {
    const int cb = t & 1, nb = cb ^ 1;
    const int tn = (t + 1 < NT) ? t + 1 : 0;   // wrap: dead-buffer stage
    const long kc = (long)tn * 32;

    // ---------------- phase 1 : ah*bh ----------------
    if constexpr (AMODE == 0) {
      asm volatile("s_waitcnt vmcnt(2) lgkmcnt(0)" ::: "memory");
    } else {
      asm volatile("s_waitcnt vmcnt(4)" ::: "memory");
    }
    __builtin_amdgcn_sched_barrier(0);
    __builtin_amdgcn_s_barrier();
    __builtin_amdgcn_sched_barrier(0);
    if constexpr (AMODE == 0) {
      g2l16(BTh + boff0 + kc, &lBh[nb][e0]);
      g2l16(BTh + boff1 + kc, &lBh[nb][e1]);
      g2l16(BTl + boff0 + kc, &lBl[nb][e0]);
      g2l16(BTl + boff1 + kc, &lBl[nb][e1]);
    } else {
      g2l16(Ah + aoff0 + kc, &lAh[nb][e0]);
      g2l16(Ah + aoff1 + kc, &lAh[nb][e1]);
      g2l16(BTh + boff0 + kc, &lBh[nb][e0]);
      g2l16(BTh + boff1 + kc, &lBh[nb][e1]);
    }
#pragma unroll
    for (int i = 0; i < 8; ++i)
      ah[i] = *(const bf16x8*)&lAh[cb][(wmw * 128 + i * 16 + lr) * 32 + kS];
#pragma unroll
    for (int j = 0; j < 4; ++j)
      bh[j] = *(const bf16x8*)&lBh[cb][(wnw * 64 + j * 16 + lr) * 32 + kS];
    __builtin_amdgcn_s_setprio(1);
#pragma unroll
    for (int i = 0; i < 8; ++i)
#pragma unroll
      for (int j = 0; j < 4; ++j)
        acc[i][j] = __builtin_amdgcn_mfma_f32_16x16x32_bf16(ah[i], bh[j], acc[i][j], 0, 0, 0);
    __builtin_amdgcn_s_setprio(0);
    if constexpr (AMODE == 0) mixA(kc, nb);

    // ---------------- phase 2 : al*bh + ah*bl ----------------
    asm volatile("s_waitcnt vmcnt(4)" ::: "memory");
    __builtin_amdgcn_sched_barrier(0);
    __builtin_amdgcn_s_barrier();
    __builtin_amdgcn_sched_barrier(0);
    if constexpr (AMODE == 1) {
      g2l16(Al + aoff0 + kc, &lAl[nb][e0]);
      g2l16(Al + aoff1 + kc, &lAl[nb][e1]);
      g2l16(BTl + boff0 + kc, &lBl[nb][e0]);
      g2l16(BTl + boff1 + kc, &lBl[nb][e1]);
    }
    bf16x8 al[8], bl[4];
#pragma unroll
    for (int i = 0; i < 8; ++i)
      al[i] = *(const bf16x8*)&lAl[cb][(wmw * 128 + i * 16 + lr) * 32 + kS];
#pragma unroll
    for (int j = 0; j < 4; ++j)
      bl[j] = *(const bf16x8*)&lBl[cb][(wnw * 64 + j * 16 + lr) * 32 + kS];
    __builtin_amdgcn_s_setprio(1);
#pragma unroll
    for (int i = 0; i < 8; ++i) {
#pragma unroll
      for (int j = 0; j < 4; ++j)
        acc[i][j] = __builtin_amdgcn_mfma_f32_16x16x32_bf16(al[i], bh[j], acc[i][j], 0, 0, 0);
#pragma unroll
      for (int j = 0; j < 4; ++j)
        acc[i][j] = __builtin_amdgcn_mfma_f32_16x16x32_bf16(ah[i], bl[j], acc[i][j], 0, 0, 0);
    }
    __builtin_amdgcn_s_setprio(0);
  }

  // C/D layout: col = lane&15, row = (lane>>4)*4 + reg   [m89-verified]
  const int qr = lane >> 4;
  const int cnn = lane & 15;
#pragma unroll
  for (int i = 0; i < 8; ++i) {
#pragma unroll
    for (int j = 0; j < 4; ++j) {
#pragma unroll
      for (int rg = 0; rg < 4; ++rg) {
        long row = m0 + wmw * 128 + i * 16 + qr * 4 + rg;
        int col = n0 + wnw * 64 + j * 16 + cnn;
        long off = row * Cn + col;
        float vv = acc[i][j][rg];
        if constexpr (EMODE == 0) {
          ((bf16_t*)Cp)[off] = (bf16_t)vv;
        } else if constexpr (EMODE == 1) {
          float z = (float)Zh[off] + (float)Zl[off];
          float zg = vv / (1.f + __expf(-vv)) * z;
          bf16_t hi = (bf16_t)zg;
          Gh[off] = hi;
          Gl[off] = (bf16_t)(zg - (float)hi);
        } else if constexpr (EMODE == 2) {
          ((float*)Cp)[off] = vv;
        } else {   // 3: split store
          bf16_t hi = (bf16_t)vv;
          Gh[off] = hi;
          Gl[off] = (bf16_t)(vv - (float)hi);
        }
      }
    }
  }
}

// ---------------------------------------------------------------------------
// wkv5 recurrence + fused /8 + GroupNorm(64, one-pass) + ln scale/shift.
// One block per (b,h), 512 threads (round-4 structure; 1024 regressed:
// LDS pipe is the bottleneck, not occupancy). Thread (j=tid>>3, ic=tid&7)
// owns S[i0..i0+7][j] fp32. All sum-reductions now run on the VALU via DPP
// (quad_perm xor1/xor2, row_half_mirror, row_mirror) instead of ds_swizzle
// -- removes 3 LDS ops/timestep/wave (inner), 3 (commit), and 8 of 12 per
// GN value; only xor16/xor32 remain as cross-row shuffles.
// j-invariant ap_t = r_t . (u * k_t) hoisted into the staging commit and
// broadcast via sA. r (hi+lo), k, v staged per 64-step chunk in LDS fp32,
// double-buffered, register prefetch 2 chunks ahead. GroupNorm via one
// interleaved tree (E[x^2]-E[x]^2, clamped >= 0). z written SPLIT hi/lo
// in-place over consumed rh-slot/k-slot.
// ---------------------------------------------------------------------------
__global__ __launch_bounds__(512)
void wkv5(const bf16_t* Rh, const bf16_t* __restrict__ Rl,
          const bf16_t* Km, const bf16_t* __restrict__ Vm,
          const float* __restrict__ decay, const float* __restrict__ faaaa,
          const float* __restrict__ lw, const float* __restrict__ lb,
          bf16_t* Zh, bf16_t* Zl)
{
  const int bh = blockIdx.x;
  const int b = bh >> 5;          // H = 32
  const int h = bh & 31;
  const int tid = threadIdx.x;
  const int j = tid >> 3;         // value column 0..63
  const int ic = tid & 7;         // i-slice 0..7
  const int i0 = ic * 8;

  float w[8], u[8], S[8];
#pragma unroll
  for (int q = 0; q < 8; ++q) {
    w[q] = expf(-expf(decay[h * 64 + i0 + q]));
    u[q] = faaaa[h * 64 + i0 + q];
    S[q] = 0.f;
  }

  __shared__ __align__(16) float sR[2][CT * 64];   // 32 KB
  __shared__ __align__(16) float sK[2][CT * 64];   // 32 KB
  __shared__ __align__(16) float sV[2][CT * 64];   // 32 KB
  __shared__ __align__(16) float sY[CT * 64];      // 16 KB
  __shared__ float sA[2][CT];                      // 0.5 KB  (ap per t)

  const int e = tid * 8;          // 512*8 = 4096 = CT*64
  const int tl = e >> 6;          // = tid>>3 : timestep within chunk
  const int cc = e & 63;          // = (tid&7)*8 : channel slice (== i0)
  const long gbase = (long)b * Tn * Cn + h * 64 + cc;

  const int wv = tid >> 6;        // wave 0..7
  const int ln = tid & 63;
  const float lwv = lw[h * 64 + ln];
  const float lbv = lb[h * 64 + ln];

  bf16x8 prh, prl, pk, pv;
  auto issue = [&](int cch) {
    const long g = gbase + (long)(cch * CT + tl) * Cn;
    prh = *(const bf16x8*)&Rh[g];
    prl = *(const bf16x8*)&Rl[g];
    pk  = *(const bf16x8*)&Km[g];
    pv  = *(const bf16x8*)&Vm[g];
  };
  auto commit = [&](int bufA) {
    float apv = 0.f;
#pragma unroll
    for (int q = 0; q < 8; ++q) {
      float rf = (float)prh[q] + (float)prl[q];
      float kf = (float)pk[q];
      sR[bufA][e + q] = rf;
      sK[bufA][e + q] = kf;
      sV[bufA][e + q] = (float)pv[q];
      apv += (rf * u[q]) * kf;    // thread's u-slice matches cc == i0
    }
    apv = dppadd<0xB1>(apv);      // xor1  (VALU)
    apv = dppadd<0x4E>(apv);      // xor2  (VALU)
    apv = dppadd<0x141>(apv);     // 8-group via row_half_mirror (VALU)
    if (ic == 0) sA[bufA][tl] = apv;
  };

  issue(0); commit(0);
  __syncthreads();
  issue(1);

  const int NC = Tn / CT;   // 32
  for (int cch = 0; cch < NC; ++cch) {
    const int buf = cch & 1;
#pragma unroll 4
    for (int t = 0; t < CT; ++t) {
      float rr[8], kk[8];
      *(f32x4*)&rr[0] = *(const f32x4*)&sR[buf][t * 64 + i0];
      *(f32x4*)&rr[4] = *(const f32x4*)&sR[buf][t * 64 + i0 + 4];
      *(f32x4*)&kk[0] = *(const f32x4*)&sK[buf][t * 64 + i0];
      *(f32x4*)&kk[4] = *(const f32x4*)&sK[buf][t * 64 + i0 + 4];
      float vj = sV[buf][t * 64 + j];
      float yp = 0.f;
#pragma unroll
      for (int q = 0; q < 8; ++q) {
        yp += rr[q] * S[q];
        S[q] = w[q] * S[q] + kk[q] * vj;
      }
      yp = dppadd<0xB1>(yp);      // xor1  (VALU)
      yp = dppadd<0x4E>(yp);      // xor2  (VALU)
      yp = dppadd<0x141>(yp);     // 8-group (VALU)
      if (ic == 0) sY[t * 64 + j] = (yp + sA[buf][t] * vj) * 0.125f;
    }
    if (cch + 1 < NC) commit((cch + 1) & 1);
    __syncthreads();
    if (cch + 2 < NC) issue(cch + 2);

    const long zrow0 = ((long)b * Tn + (long)cch * CT) * Cn + h * 64 + ln;
#pragma unroll
    for (int q = 0; q < 8; ++q) {
      const int t = wv * 8 + q;
      float val = sY[t * 64 + ln];
      float s = val, s2 = val * val;
      s = dppadd<0xB1>(s);   s2 = dppadd<0xB1>(s2);    // xor1
      s = dppadd<0x4E>(s);   s2 = dppadd<0x4E>(s2);    // xor2
      s = dppadd<0x141>(s);  s2 = dppadd<0x141>(s2);   // 8-group
      s = dppadd<0x140>(s);  s2 = dppadd<0x140>(s2);   // 16-group (mirror)
      s  += __shfl_xor(s, 16);  s2 += __shfl_xor(s2, 16);
      s  += __shfl_xor(s, 32);  s2 += __shfl_xor(s2, 32);
      float mu = s * (1.f / 64.f);
      float var = fmaxf(s2 * (1.f / 64.f) - mu * mu, 0.f);
      float rs = rsqrtf(var + 1e-5f);
      float zv = (val - mu) * rs * lwv + lbv;
      bf16_t zh = (bf16_t)zv;
      Zh[zrow0 + (long)t * Cn] = zh;
      Zl[zrow0 + (long)t * Cn] = (bf16_t)(zv - (float)zh);
    }
    __syncthreads();
  }
}

// ---------------------------------------------------------------------------
extern "C" void kernel_launch(void* const* d_in, const int* in_sizes, int n_in,
                              void* d_out, int out_size, void* d_ws, size_t ws_size,
                              hipStream_t stream)
{
  const float* x    = (const float*)d_in[0];
  const float* tmk  = (const float*)d_in[1];
  const float* tmv  = (const float*)d_in[2];
  const float* tmr  = (const float*)d_in[3];
  const float* tmg  = (const float*)d_in[4];
  const float* tdec = (const float*)d_in[5];
  const float* tfaa = (const float*)d_in[6];
  const float* Wr   = (const float*)d_in[7];
  const float* Wk   = (const float*)d_in[8];
  const float* Wv   = (const float*)d_in[9];
  const float* Wg   = (const float*)d_in[10];
  const float* Wo   = (const float*)d_in[11];
  const float* lnw  = (const float*)d_in[12];
  const float* lnb  = (const float*)d_in[13];

  // ws layout (218.1 MB):
  //   [0, 41.9MB)      wTh : 5 transposed weight hi
  //   [41.9, 83.9MB)   wTl : 5 transposed weight lo
  //   sl0: v,    then zg_hi
  //   sl1: r_lo, then zg_lo
  // d_out (134 MB fp32 = 2 bf16 slots):
  //   d0a: r_hi, then z_hi;  d0b: k, then z_lo;  finally fp32 out.
  char* ws = (char*)d_ws;
  const long WSZ = (long)Cn * Cn;
  const long SZB = SZ * 2;                  // 67,108,864 B per bf16 slot
  bf16_t* wTh = (bf16_t*)ws;
  bf16_t* wTl = (bf16_t*)(ws + 5 * WSZ * 2);
  bf16_t* sl0 = (bf16_t*)(ws + 10 * WSZ * 2);
  bf16_t* sl1 = (bf16_t*)(ws + 10 * WSZ * 2 + SZB);
  bf16_t* d0a = (bf16_t*)d_out;
  bf16_t* d0b = (bf16_t*)d_out + SZ;

  const dim3 gGrid(8, 64, 1);   // 256x256 tiles over [16384, 2048]

  transps<<<dim3(32, 32, 5), 256, 0, stream>>>(Wr, Wk, Wv, Wg, Wo, wTh, wTl);

  // r = mix(x,tmr) @ Wr, split -> hi d0a, lo sl1
  gemmx<0, 3><<<gGrid, 512, 0, stream>>>(x, tmr, nullptr, nullptr,
                                         wTh + 0 * WSZ, wTl + 0 * WSZ, nullptr,
                                         nullptr, nullptr, d0a, sl1);
  // k = mix(x,tmk) @ Wk -> bf16 d0b
  gemmx<0, 0><<<gGrid, 512, 0, stream>>>(x, tmk, nullptr, nullptr,
                                         wTh + 1 * WSZ, wTl + 1 * WSZ, d0b,
                                         nullptr, nullptr, nullptr, nullptr);
  // v = mix(x,tmv) @ Wv -> bf16 sl0
  gemmx<0, 0><<<gGrid, 512, 0, stream>>>(x, tmv, nullptr, nullptr,
                                         wTh + 2 * WSZ, wTl + 2 * WSZ, sl0,
                                         nullptr, nullptr, nullptr, nullptr);

  // wkv5 + /8 + groupnorm -> z split: hi over d0a (r_hi), lo over d0b (k)
  wkv5<<<256, 512, 0, stream>>>(d0a, sl1, d0b, sl0, tdec, tfaa, lnw, lnb,
                                d0a, d0b);

  // zg = silu(mix(x,tmg) @ Wg) * (z_hi+z_lo), split -> hi sl0, lo sl1
  gemmx<0, 1><<<gGrid, 512, 0, stream>>>(x, tmg, nullptr, nullptr,
                                         wTh + 3 * WSZ, wTl + 3 * WSZ, nullptr,
                                         d0a, d0b, sl0, sl1);

  // out = (zg_hi+zg_lo) @ Wo -> fp32 d_out
  gemmx<1, 2><<<gGrid, 512, 0, stream>>>(nullptr, nullptr, sl0, sl1,
                                         wTh + 4 * WSZ, wTl + 4 * WSZ, d_out,
                                         nullptr, nullptr, nullptr, nullptr);
}